// Round 11
// baseline (548.193 us; speedup 1.0000x reference)
//
#include <hip/hip_runtime.h>
#include <hip/hip_bf16.h>
#include <math.h>

#define N_NODES 100000
#define DIM 64
#define E_EDGES 1600000
#define N_ADJ 4
#define NB 391               // ceil(100000/256) buckets of 256 rows
#define NBTOT (N_ADJ * NB)   // 1564
#define P1_BLK 1024
#define P1_CHUNK 12800
#define P1_GRIDX 125         // 125 * 12800 = 1.6M
#define CAP 5120             // fixed-cap slots/bucket: mean 4096 + 16 sigma
#define SORT_STAGE 5120      // per-bucket LDS stage (40 KB)
#define SORT_BLK 512
#define GEMM_BLOCKS (N_NODES / 16)   // 6250; block GEMM_BLOCKS is the init block
#define NVOFF ((u32)N_NODES * DIM)   // u16 elements between s0 and s1

typedef unsigned short u16;
typedef unsigned int u32;
typedef float f32x4 __attribute__((ext_vector_type(4)));   // native vec for nt-store

// ---------------- GEMM: s0 = bf16(x @ W + b); last block does init ----------
// Register-blocked: one Ws read serves 4 row-FMAs (kernel was LDS-read-bound).
__global__ __launch_bounds__(256) void gemm_init_kernel(
    const float* __restrict__ x, const float* __restrict__ W,
    const float* __restrict__ b, u16* __restrict__ h,
    const int* __restrict__ iseq, const int* __restrict__ ires,
    int* __restrict__ used, int* __restrict__ gcnt,
    int* __restrict__ bbase, int* __restrict__ cursor, const int mode) {
    const int tid = threadIdx.x;
    if (blockIdx.x == GEMM_BLOCKS) {           // ---- init block ----
        for (int k = tid; k < NBTOT; k += 256) {
            gcnt[k] = 0;
            if (mode) { bbase[k] = k * CAP; cursor[k] = k * CAP; }
        }
        if (tid == 0) {
            if (mode) bbase[NBTOT] = NBTOT * CAP;
            used[0] = used[1] = used[2] = used[3] = 0;
            used[iseq[0]] = 1; used[iseq[1]] = 1;
            used[iseq[2]] = 1; used[iseq[3]] = 1;
            used[ires[0]] = 1; used[ires[1]] = 1;
        }
        return;
    }
    __shared__ float Ws[DIM * DIM];
    __shared__ float xs[16 * DIM];
    const long row0 = (long)blockIdx.x * 16;
    for (int i = tid; i < DIM * DIM; i += 256) Ws[i] = W[i];
    for (int i = tid; i < 16 * DIM; i += 256) xs[i] = x[row0 * DIM + i];
    __syncthreads();
    const int lane = tid & 63;
    const int grp  = tid >> 6;
    const float bias = b[lane];
    float acc0 = bias, acc1 = bias, acc2 = bias, acc3 = bias;
    const float* xr = xs + grp * 4 * DIM;
    #pragma unroll
    for (int k = 0; k < DIM; ++k) {
        const float w = Ws[k * DIM + lane];    // 1 LDS read serves 4 FMAs
        acc0 = fmaf(xr[k],           w, acc0);
        acc1 = fmaf(xr[DIM + k],     w, acc1);
        acc2 = fmaf(xr[2 * DIM + k], w, acc2);
        acc3 = fmaf(xr[3 * DIM + k], w, acc3);
    }
    const long rbase = (row0 + grp * 4) * DIM + lane;
    __hip_bfloat16 b0 = __float2bfloat16(acc0);
    __hip_bfloat16 b1 = __float2bfloat16(acc1);
    __hip_bfloat16 b2 = __float2bfloat16(acc2);
    __hip_bfloat16 b3 = __float2bfloat16(acc3);
    h[rbase]           = *(u16*)&b0;
    h[rbase + DIM]     = *(u16*)&b1;
    h[rbase + 2 * DIM] = *(u16*)&b2;
    h[rbase + 3 * DIM] = *(u16*)&b3;
}

// ---- hist (dense fallback only): bucket counts -> gcnt ----
__global__ __launch_bounds__(1024) void hist_kernel(
    const int* __restrict__ rows, int* __restrict__ gcnt,
    const int* __restrict__ used) {
    __shared__ int h[NB];
    const int a = blockIdx.y;
    if (!used[a]) return;
    const int tid = threadIdx.x;
    const long e0 = (long)a * E_EDGES + (long)blockIdx.x * P1_CHUNK;
    for (int i = tid; i < NB; i += P1_BLK) h[i] = 0;
    __syncthreads();
    for (int i = tid; i < P1_CHUNK; i += P1_BLK)
        atomicAdd(&h[rows[e0 + i] >> 8], 1);
    __syncthreads();
    for (int bk = tid; bk < NB; bk += P1_BLK) {
        const int c = h[bk];
        if (c) atomicAdd(&gcnt[a * NB + bk], c);
    }
}

// ---- scan (dense fallback only): exclusive scan of 1564 counts ----
__global__ __launch_bounds__(1024) void scan_kernel(
    const int* __restrict__ gcnt, int* __restrict__ bbase,
    int* __restrict__ cursor) {
    __shared__ int wsum[16];
    const int tid = threadIdx.x, lane = tid & 63, wave = tid >> 6;
    int pre[2];
    int tsum = 0;
    #pragma unroll
    for (int k = 0; k < 2; ++k) {
        const int idx = tid * 2 + k;
        const int v = (idx < NBTOT) ? gcnt[idx] : 0;
        pre[k] = tsum;
        tsum += v;
    }
    int incl = tsum;
    #pragma unroll
    for (int o = 1; o < 64; o <<= 1) {
        const int t = __shfl_up(incl, o);
        if (lane >= o) incl += t;
    }
    if (lane == 63) wsum[wave] = incl;
    __syncthreads();
    if (tid == 0) {
        int run = 0;
        #pragma unroll
        for (int w = 0; w < 16; ++w) { const int t = wsum[w]; wsum[w] = run; run += t; }
    }
    __syncthreads();
    const int texcl = incl - tsum + wsum[wave];
    #pragma unroll
    for (int k = 0; k < 2; ++k) {
        const int idx = tid * 2 + k;
        if (idx < NBTOT) {
            const int v = texcl + pre[k];
            bbase[idx]  = v;
            cursor[idx] = v;
        }
    }
    if (tid == 0) bbase[NBTOT] = N_ADJ * E_EDGES;
}

// ---- place: reserve per-(block,bucket) runs off preinit'd cursor, pack ----
// Record = (col<<8 | r&255, val), written nontemporal (bins never L2-fits;
// keep L2 for s0/s1). Row keys cached in LDS across the two passes.
__global__ __launch_bounds__(1024) void place_kernel(
    const int* __restrict__ rows, const int* __restrict__ cols,
    const float* __restrict__ vals, int* __restrict__ cursor,
    int2* __restrict__ bins, const int* __restrict__ used, const int cap) {
    __shared__ int h[NB];
    __shared__ int rcache[P1_CHUNK];   // 51.2 KB
    const int a = blockIdx.y;
    if (!used[a]) return;
    const int tid = threadIdx.x;
    const long e0 = (long)a * E_EDGES + (long)blockIdx.x * P1_CHUNK;
    for (int i = tid; i < NB; i += P1_BLK) h[i] = 0;
    __syncthreads();
    for (int i = tid; i < P1_CHUNK; i += P1_BLK) {
        const int r = rows[e0 + i];
        rcache[i] = r;
        atomicAdd(&h[r >> 8], 1);
    }
    __syncthreads();
    for (int bk = tid; bk < NB; bk += P1_BLK) {
        const int c = h[bk];
        if (c) h[bk] = atomicAdd(&cursor[a * NB + bk], c);  // abs base of run
    }
    __syncthreads();
    for (int i = tid; i < P1_CHUNK; i += P1_BLK) {
        const int r  = rcache[i];
        const int bk = r >> 8;
        const int slot = atomicAdd(&h[bk], 1);              // absolute bins index
        if (!cap || slot < (a * NB + bk + 1) * cap) {
            const long long rec = (long long)(u32)((cols[e0 + i] << 8) | (r & 255))
                                | ((long long)(u32)__float_as_int(vals[e0 + i]) << 32);
            __builtin_nontemporal_store(rec, (long long*)(bins + slot));
        }
    }
}

// ---- sort: per-bucket counting sort by r&255, emit per-row (start,count);
//      nt stage-in + nt writeback (bins is stream-once at 51 MB);
//      records rewritten to (col<<6, val) for the gather core ----
__global__ __launch_bounds__(SORT_BLK) void sort_kernel(
    int2* __restrict__ bins, const int* __restrict__ bbase,
    const int* __restrict__ cursor, int2* __restrict__ rowinfo,
    const int* __restrict__ used) {
    __shared__ int2 stage[SORT_STAGE];
    __shared__ int h[256], off[256], cur[256], wsc[4];
    const int a   = blockIdx.x / NB;
    if (!used[a]) return;
    const int tid = threadIdx.x;
    const int bk  = blockIdx.x % NB;
    const int p0  = bbase[blockIdx.x];
    const int n   = min(cursor[blockIdx.x] - p0, SORT_STAGE);

    if (tid < 256) h[tid] = 0;
    __syncthreads();
    for (int i = tid; i < n; i += SORT_BLK) {
        const long long raw =
            __builtin_nontemporal_load((const long long*)(bins + p0 + i));
        const int ex = (int)raw;
        stage[i] = make_int2(ex, (int)(raw >> 32));
        atomicAdd(&h[ex & 255], 1);
    }
    __syncthreads();
    {
        const int lane = tid & 63, wave = tid >> 6;
        const int v = (tid < 256) ? h[tid] : 0;
        int incl = v;
        #pragma unroll
        for (int o = 1; o < 64; o <<= 1) {
            const int t = __shfl_up(incl, o);
            if (lane >= o) incl += t;
        }
        if (tid < 256 && lane == 63) wsc[wave] = incl;
        __syncthreads();
        if (tid == 0) {
            int run = 0;
            #pragma unroll
            for (int w = 0; w < 4; ++w) { const int t = wsc[w]; wsc[w] = run; run += t; }
        }
        __syncthreads();
        if (tid < 256) {
            const int e = incl - v + wsc[wave];
            off[tid] = e;
            cur[tid] = e;
        }
    }
    __syncthreads();
    for (int i = tid; i < n; i += SORT_BLK) {
        const int2 e = stage[i];
        const int rank = atomicAdd(&cur[e.x & 255], 1);
        const long long rec = (long long)(u32)((((u32)e.x >> 8) << 6))
                            | ((long long)(u32)e.y << 32);
        __builtin_nontemporal_store(rec, (long long*)(bins + p0 + rank));
    }
    if (tid < 256) {
        const int row = (bk << 8) + tid;
        if (row < N_NODES)
            rowinfo[a * N_NODES + row] = make_int2(p0 + off[tid], h[tid]);
    }
}

// ---------------- Pull gather cores ----------
// 4-segment core (fused): round-2 structure, verbatim.
__device__ __forceinline__ void gather4(
    const u16* __restrict__ base, const u32 nvoff,
    const int2* __restrict__ bins,
    const int2 i0, const int2 i1, const int2 i2, const int2 i3,
    const int grp, const int dsub, float acc[8])
{
    const int c1 = i0.y;
    const int c2 = c1 + i1.y;
    const int c3 = c2 + i2.y;
    const int m  = c3 + i3.y;
    const int b0 = i0.x;
    const int b1 = i1.x - c1;
    const int b2 = i2.x - c2;
    const int b3 = i3.x - c3;

    for (int T = grp; T < m; T += 32) {
        int x0, x1, x2, x3;
        float v0, v1, v2, v3;
        u32 so0, so1, so2, so3;
        #define SLOT(TT, XX, VV, SS) {                                        \
            const int t = (TT);                                               \
            int pos = b0 + t;                                                 \
            if (t >= c1) pos = b1 + t;                                        \
            if (t >= c2) pos = b2 + t;                                        \
            if (t >= c3) pos = b3 + t;                                        \
            long long raw = 0;                                                \
            if (t < m)                                                        \
                raw = __builtin_nontemporal_load((const long long*)(bins + pos)); \
            XX = (int)raw;                                                    \
            VV = __int_as_float((int)(raw >> 32));                            \
            SS = (t < c2) ? nvoff : 0u; }
        SLOT(T,      x0, v0, so0)
        SLOT(T + 8,  x1, v1, so1)
        SLOT(T + 16, x2, v2, so2)
        SLOT(T + 24, x3, v3, so3)
        #undef SLOT
        const uint4 w0 = *(const uint4*)(base + (so0 + ((u32)x0 & 0xFFFFFFC0u) + (u32)dsub));
        const uint4 w1 = *(const uint4*)(base + (so1 + ((u32)x1 & 0xFFFFFFC0u) + (u32)dsub));
        const uint4 w2 = *(const uint4*)(base + (so2 + ((u32)x2 & 0xFFFFFFC0u) + (u32)dsub));
        const uint4 w3 = *(const uint4*)(base + (so3 + ((u32)x3 & 0xFFFFFFC0u) + (u32)dsub));
        #define FMA8(W, V) {                                                  \
            acc[0] = fmaf((V), __int_as_float((W).x << 16),         acc[0]);  \
            acc[1] = fmaf((V), __int_as_float((W).x & 0xffff0000u), acc[1]);  \
            acc[2] = fmaf((V), __int_as_float((W).y << 16),         acc[2]);  \
            acc[3] = fmaf((V), __int_as_float((W).y & 0xffff0000u), acc[3]);  \
            acc[4] = fmaf((V), __int_as_float((W).z << 16),         acc[4]);  \
            acc[5] = fmaf((V), __int_as_float((W).z & 0xffff0000u), acc[5]);  \
            acc[6] = fmaf((V), __int_as_float((W).w << 16),         acc[6]);  \
            acc[7] = fmaf((V), __int_as_float((W).w & 0xffff0000u), acc[7]); }
        FMA8(w0, v0)
        FMA8(w1, v1)
        FMA8(w2, v2)
        FMA8(w3, v3)
        #undef FMA8
    }
}

// 2-segment core (gather_op): no 4-way cascade, no source select.
__device__ __forceinline__ void gather2(
    const u16* __restrict__ base, const int2* __restrict__ bins,
    const int2 i0, const int2 i1,
    const int grp, const int dsub, float acc[8])
{
    const int c1 = i0.y;
    const int m  = c1 + i1.y;
    const int b0 = i0.x;
    const int b1 = i1.x - c1;

    for (int T = grp; T < m; T += 32) {
        int x0, x1, x2, x3;
        float v0, v1, v2, v3;
        #define SLOT2(TT, XX, VV) {                                           \
            const int t = (TT);                                               \
            const int pos = (t >= c1) ? (b1 + t) : (b0 + t);                  \
            long long raw = 0;                                                \
            if (t < m)                                                        \
                raw = __builtin_nontemporal_load((const long long*)(bins + pos)); \
            XX = (int)raw;                                                    \
            VV = __int_as_float((int)(raw >> 32)); }
        SLOT2(T,      x0, v0)
        SLOT2(T + 8,  x1, v1)
        SLOT2(T + 16, x2, v2)
        SLOT2(T + 24, x3, v3)
        #undef SLOT2
        const uint4 w0 = *(const uint4*)(base + (((u32)x0 & 0xFFFFFFC0u) + (u32)dsub));
        const uint4 w1 = *(const uint4*)(base + (((u32)x1 & 0xFFFFFFC0u) + (u32)dsub));
        const uint4 w2 = *(const uint4*)(base + (((u32)x2 & 0xFFFFFFC0u) + (u32)dsub));
        const uint4 w3 = *(const uint4*)(base + (((u32)x3 & 0xFFFFFFC0u) + (u32)dsub));
        #define FMA8(W, V) {                                                  \
            acc[0] = fmaf((V), __int_as_float((W).x << 16),         acc[0]);  \
            acc[1] = fmaf((V), __int_as_float((W).x & 0xffff0000u), acc[1]);  \
            acc[2] = fmaf((V), __int_as_float((W).y << 16),         acc[2]);  \
            acc[3] = fmaf((V), __int_as_float((W).y & 0xffff0000u), acc[3]);  \
            acc[4] = fmaf((V), __int_as_float((W).z << 16),         acc[4]);  \
            acc[5] = fmaf((V), __int_as_float((W).z & 0xffff0000u), acc[5]);  \
            acc[6] = fmaf((V), __int_as_float((W).w << 16),         acc[6]);  \
            acc[7] = fmaf((V), __int_as_float((W).w & 0xffff0000u), acc[7]); }
        FMA8(w0, v0)
        FMA8(w1, v1)
        FMA8(w2, v2)
        FMA8(w3, v3)
        #undef FMA8
    }
}

__device__ __forceinline__ void reduce_groups8(float acc[8]) {
    #pragma unroll
    for (int d = 0; d < 8; ++d) {
        acc[d] += __shfl_xor(acc[d], 8);
        acc[d] += __shfl_xor(acc[d], 16);
        acc[d] += __shfl_xor(acc[d], 32);
    }
}

// s1 = bf16(0.5*(A[i0]+A[i1]) @ s0)
__global__ __launch_bounds__(256) void gather_op_kernel(
    const u16* __restrict__ s0, u16* __restrict__ dst,
    const int2* __restrict__ bins, const int2* __restrict__ rowinfo,
    const int* __restrict__ idx) {
    const int lane = threadIdx.x & 63;
    const int row  = blockIdx.x * 4 + (threadIdx.x >> 6);
    const int grp  = lane >> 3;
    const int sub  = lane & 7;
    const int dsub = sub << 3;
    const int2 i0 = rowinfo[idx[0] * N_NODES + row];
    const int2 i1 = rowinfo[idx[1] * N_NODES + row];
    float acc[8] = {0.f, 0.f, 0.f, 0.f, 0.f, 0.f, 0.f, 0.f};
    gather2(s0, bins, i0, i1, grp, dsub, acc);
    reduce_groups8(acc);
    if (grp == 0) {
        u32 p[4];
        #pragma unroll
        for (int q = 0; q < 4; ++q) {
            __hip_bfloat16 blo = __float2bfloat16(0.5f * acc[2 * q]);
            __hip_bfloat16 bhi = __float2bfloat16(0.5f * acc[2 * q + 1]);
            p[q] = (u32)(*(u16*)&blo) | ((u32)(*(u16*)&bhi) << 16);
        }
        *(uint4*)(dst + (long)row * DIM + dsub) = make_uint4(p[0], p[1], p[2], p[3]);
    }
}

// out = gelu(LN(0.5*(seq@s1) + 0.5*(res@s0)))
__global__ __launch_bounds__(256) void fused_op_ln_gelu_kernel(
    const u16* __restrict__ s0, float* __restrict__ out,
    const int2* __restrict__ bins, const int2* __restrict__ rowinfo,
    const int* __restrict__ idx_seq1, const int* __restrict__ idx_res,
    const float* __restrict__ gamma, const float* __restrict__ beta) {
    const int lane = threadIdx.x & 63;
    const int row  = blockIdx.x * 4 + (threadIdx.x >> 6);
    const int grp  = lane >> 3;
    const int sub  = lane & 7;
    const int dsub = sub << 3;
    // segments 0,1 gather from s1 (= s0 + NVOFF via nvoff), 2,3 from s0
    const int2 i0 = rowinfo[idx_seq1[0] * N_NODES + row];
    const int2 i1 = rowinfo[idx_seq1[1] * N_NODES + row];
    const int2 i2 = rowinfo[idx_res[0]  * N_NODES + row];
    const int2 i3 = rowinfo[idx_res[1]  * N_NODES + row];
    float acc[8] = {0.f, 0.f, 0.f, 0.f, 0.f, 0.f, 0.f, 0.f};
    gather4(s0, NVOFF, bins, i0, i1, i2, i3, grp, dsub, acc);
    reduce_groups8(acc);
    #pragma unroll
    for (int d = 0; d < 8; ++d) acc[d] *= 0.5f;
    float s = 0.f, s2 = 0.f;
    #pragma unroll
    for (int d = 0; d < 8; ++d) { s += acc[d]; s2 += acc[d] * acc[d]; }
    s  += __shfl_xor(s, 1);  s  += __shfl_xor(s, 2);  s  += __shfl_xor(s, 4);
    s2 += __shfl_xor(s2, 1); s2 += __shfl_xor(s2, 2); s2 += __shfl_xor(s2, 4);
    const float mu  = s * (1.0f / DIM);
    const float var = s2 * (1.0f / DIM) - mu * mu;
    const float inv = rsqrtf(var + 1e-5f);
    if (grp == 0) {
        const float4 gm0 = ((const float4*)gamma)[sub * 2];
        const float4 gm1 = ((const float4*)gamma)[sub * 2 + 1];
        const float4 bt0 = ((const float4*)beta)[sub * 2];
        const float4 bt1 = ((const float4*)beta)[sub * 2 + 1];
        float y[8];
        y[0] = (acc[0] - mu) * inv * gm0.x + bt0.x;
        y[1] = (acc[1] - mu) * inv * gm0.y + bt0.y;
        y[2] = (acc[2] - mu) * inv * gm0.z + bt0.z;
        y[3] = (acc[3] - mu) * inv * gm0.w + bt0.w;
        y[4] = (acc[4] - mu) * inv * gm1.x + bt1.x;
        y[5] = (acc[5] - mu) * inv * gm1.y + bt1.y;
        y[6] = (acc[6] - mu) * inv * gm1.z + bt1.z;
        y[7] = (acc[7] - mu) * inv * gm1.w + bt1.w;
        f32x4 o0, o1;
        o0.x = 0.5f * y[0] * (1.0f + erff(y[0] * 0.70710678118654752f));
        o0.y = 0.5f * y[1] * (1.0f + erff(y[1] * 0.70710678118654752f));
        o0.z = 0.5f * y[2] * (1.0f + erff(y[2] * 0.70710678118654752f));
        o0.w = 0.5f * y[3] * (1.0f + erff(y[3] * 0.70710678118654752f));
        o1.x = 0.5f * y[4] * (1.0f + erff(y[4] * 0.70710678118654752f));
        o1.y = 0.5f * y[5] * (1.0f + erff(y[5] * 0.70710678118654752f));
        o1.z = 0.5f * y[6] * (1.0f + erff(y[6] * 0.70710678118654752f));
        o1.w = 0.5f * y[7] * (1.0f + erff(y[7] * 0.70710678118654752f));
        // final output: never re-read -> nontemporal, keep L2 for gather tables
        f32x4* po = (f32x4*)(out + (long)row * DIM + dsub);
        __builtin_nontemporal_store(o0, po);
        __builtin_nontemporal_store(o1, po + 1);
    }
}

extern "C" void kernel_launch(void* const* d_in, const int* in_sizes, int n_in,
                              void* d_out, int out_size, void* d_ws, size_t ws_size,
                              hipStream_t stream) {
    const float* x     = (const float*)d_in[0];
    const float* W     = (const float*)d_in[1];
    const float* b     = (const float*)d_in[2];
    const int*   rows  = (const int*)d_in[3];
    const int*   cols  = (const int*)d_in[4];
    const float* vals  = (const float*)d_in[5];
    const float* gamma = (const float*)d_in[6];
    const float* beta  = (const float*)d_in[7];
    const int*   idxes_seq = (const int*)d_in[8];   // [2,2] flat
    const int*   idxes_res = (const int*)d_in[9];   // [1,2] flat
    float* out = (float*)d_out;

    // ---- mode select: fixed-cap bins (skip hist+scan) if workspace allows ----
    const size_t tail_bytes = (size_t)N_NODES * DIM * 2 * 2        // s0+s1
                            + (size_t)N_ADJ * N_NODES * 8          // rowinfo
                            + (size_t)(NBTOT + NBTOT + 1 + NBTOT + 4) * 4;
    const size_t fixed_need = (size_t)NBTOT * CAP * 8 + tail_bytes;
    const int mode = (ws_size >= fixed_need) ? 1 : 0;
    const size_t bins_elems = mode ? (size_t)NBTOT * CAP
                                   : (size_t)N_ADJ * E_EDGES;

    int2*  bins    = (int2*)d_ws;
    u16*   s0      = (u16*)(bins + bins_elems);                  // 12.8 MB bf16
    u16*   s1      = s0 + (size_t)N_NODES * DIM;                 // 12.8 MB (= s0 + NVOFF)
    int2*  rowinfo = (int2*)(s1 + (size_t)N_NODES * DIM);        // 3.2 MB
    int*   gcnt    = (int*)(rowinfo + (size_t)N_ADJ * N_NODES);  // 1564 ints
    int*   bbase   = gcnt + NBTOT;                               // 1565 ints
    int*   cursor  = bbase + NBTOT + 1;                          // 1564 ints
    int*   used    = cursor + NBTOT;                             // 4 ints

    // gemm + init fused: block GEMM_BLOCKS performs mask/cursor init
    gemm_init_kernel<<<GEMM_BLOCKS + 1, 256, 0, stream>>>(
        x, W, b, s0, idxes_seq, idxes_res, used, gcnt, bbase, cursor, mode);

    dim3 egrid(P1_GRIDX, N_ADJ);
    if (!mode) {
        hist_kernel<<<egrid, P1_BLK, 0, stream>>>(rows, gcnt, used);
        scan_kernel<<<1, P1_BLK, 0, stream>>>(gcnt, bbase, cursor);
    }
    place_kernel<<<egrid, P1_BLK, 0, stream>>>(rows, cols, vals, cursor, bins,
                                               used, mode ? CAP : 0);
    sort_kernel<<<NBTOT, SORT_BLK, 0, stream>>>(bins, bbase, cursor, rowinfo, used);

    // s1 = 0.5*(A[i0]+A[i1]) @ s0
    gather_op_kernel<<<N_NODES / 4, 256, 0, stream>>>(s0, s1, bins, rowinfo, idxes_seq);
    // out = gelu(LN(0.5*(A[i2]+A[i3])@s1 + 0.5*(A[r0]+A[r1])@s0))
    fused_op_ln_gelu_kernel<<<N_NODES / 4, 256, 0, stream>>>(
        s0, out, bins, rowinfo, idxes_seq + 2, idxes_res, gamma, beta);
}

// Round 13
// 375.345 us; speedup vs baseline: 1.4605x; 1.4605x over previous
//
#include <hip/hip_runtime.h>
#include <hip/hip_bf16.h>
#include <math.h>

#define N_NODES 100000
#define DIM 64
#define E_EDGES 1600000
#define N_ADJ 4
#define NB 391               // ceil(100000/256) buckets of 256 rows
#define NBTOT (N_ADJ * NB)   // 1564
#define P1_BLK 1024
#define P1_CHUNK 12800
#define P1_GRIDX 125         // 125 * 12800 = 1.6M
#define CAP 5120             // fixed-cap slots/bucket: mean 4096 + 16 sigma
#define SORT_STAGE 5120      // per-bucket LDS stage (40 KB)
#define SORT_BLK 512
#define GEMM_BLOCKS (N_NODES / 16)   // 6250; block GEMM_BLOCKS is the init block
#define NVOFF ((u32)N_NODES * DIM)   // u16 elements between s0 and s1

typedef unsigned short u16;
typedef unsigned int u32;
typedef float f32x4 __attribute__((ext_vector_type(4)));   // native vec for nt-store

// ---------------- GEMM: s0 = bf16(x @ W + b); last block does init ----------
// Register-blocked: one Ws read serves 4 row-FMAs.
__global__ __launch_bounds__(256) void gemm_init_kernel(
    const float* __restrict__ x, const float* __restrict__ W,
    const float* __restrict__ b, u16* __restrict__ h,
    const int* __restrict__ iseq, const int* __restrict__ ires,
    int* __restrict__ used, int* __restrict__ gcnt,
    int* __restrict__ bbase, int* __restrict__ cursor, const int mode) {
    const int tid = threadIdx.x;
    if (blockIdx.x == GEMM_BLOCKS) {           // ---- init block ----
        for (int k = tid; k < NBTOT; k += 256) {
            gcnt[k] = 0;
            if (mode) { bbase[k] = k * CAP; cursor[k] = k * CAP; }
        }
        if (tid == 0) {
            if (mode) bbase[NBTOT] = NBTOT * CAP;
            used[0] = used[1] = used[2] = used[3] = 0;
            used[iseq[0]] = 1; used[iseq[1]] = 1;
            used[iseq[2]] = 1; used[iseq[3]] = 1;
            used[ires[0]] = 1; used[ires[1]] = 1;
        }
        return;
    }
    __shared__ float Ws[DIM * DIM];
    __shared__ float xs[16 * DIM];
    const long row0 = (long)blockIdx.x * 16;
    for (int i = tid; i < DIM * DIM; i += 256) Ws[i] = W[i];
    for (int i = tid; i < 16 * DIM; i += 256) xs[i] = x[row0 * DIM + i];
    __syncthreads();
    const int lane = tid & 63;
    const int grp  = tid >> 6;
    const float bias = b[lane];
    float acc0 = bias, acc1 = bias, acc2 = bias, acc3 = bias;
    const float* xr = xs + grp * 4 * DIM;
    #pragma unroll
    for (int k = 0; k < DIM; ++k) {
        const float w = Ws[k * DIM + lane];    // 1 LDS read serves 4 FMAs
        acc0 = fmaf(xr[k],           w, acc0);
        acc1 = fmaf(xr[DIM + k],     w, acc1);
        acc2 = fmaf(xr[2 * DIM + k], w, acc2);
        acc3 = fmaf(xr[3 * DIM + k], w, acc3);
    }
    const long rbase = (row0 + grp * 4) * DIM + lane;
    __hip_bfloat16 b0 = __float2bfloat16(acc0);
    __hip_bfloat16 b1 = __float2bfloat16(acc1);
    __hip_bfloat16 b2 = __float2bfloat16(acc2);
    __hip_bfloat16 b3 = __float2bfloat16(acc3);
    h[rbase]           = *(u16*)&b0;
    h[rbase + DIM]     = *(u16*)&b1;
    h[rbase + 2 * DIM] = *(u16*)&b2;
    h[rbase + 3 * DIM] = *(u16*)&b3;
}

// ---- hist (dense fallback only): bucket counts -> gcnt ----
__global__ __launch_bounds__(1024) void hist_kernel(
    const int* __restrict__ rows, int* __restrict__ gcnt,
    const int* __restrict__ used) {
    __shared__ int h[NB];
    const int a = blockIdx.y;
    if (!used[a]) return;
    const int tid = threadIdx.x;
    const long e0 = (long)a * E_EDGES + (long)blockIdx.x * P1_CHUNK;
    for (int i = tid; i < NB; i += P1_BLK) h[i] = 0;
    __syncthreads();
    for (int i = tid; i < P1_CHUNK; i += P1_BLK)
        atomicAdd(&h[rows[e0 + i] >> 8], 1);
    __syncthreads();
    for (int bk = tid; bk < NB; bk += P1_BLK) {
        const int c = h[bk];
        if (c) atomicAdd(&gcnt[a * NB + bk], c);
    }
}

// ---- scan (dense fallback only): exclusive scan of 1564 counts ----
__global__ __launch_bounds__(1024) void scan_kernel(
    const int* __restrict__ gcnt, int* __restrict__ bbase,
    int* __restrict__ cursor) {
    __shared__ int wsum[16];
    const int tid = threadIdx.x, lane = tid & 63, wave = tid >> 6;
    int pre[2];
    int tsum = 0;
    #pragma unroll
    for (int k = 0; k < 2; ++k) {
        const int idx = tid * 2 + k;
        const int v = (idx < NBTOT) ? gcnt[idx] : 0;
        pre[k] = tsum;
        tsum += v;
    }
    int incl = tsum;
    #pragma unroll
    for (int o = 1; o < 64; o <<= 1) {
        const int t = __shfl_up(incl, o);
        if (lane >= o) incl += t;
    }
    if (lane == 63) wsum[wave] = incl;
    __syncthreads();
    if (tid == 0) {
        int run = 0;
        #pragma unroll
        for (int w = 0; w < 16; ++w) { const int t = wsum[w]; wsum[w] = run; run += t; }
    }
    __syncthreads();
    const int texcl = incl - tsum + wsum[wave];
    #pragma unroll
    for (int k = 0; k < 2; ++k) {
        const int idx = tid * 2 + k;
        if (idx < NBTOT) {
            const int v = texcl + pre[k];
            bbase[idx]  = v;
            cursor[idx] = v;
        }
    }
    if (tid == 0) bbase[NBTOT] = N_ADJ * E_EDGES;
}

// ---- place: reserve per-(block,bucket) runs off preinit'd cursor, pack ----
// Record = (col<<8 | r&255, val). PLAIN cacheable stores: L2 is the
// write-combining buffer for the scattered 8 B records (r11 ERRATA:
// nt-store here caused 2.5x write amplification, 35->135 us).
__global__ __launch_bounds__(1024) void place_kernel(
    const int* __restrict__ rows, const int* __restrict__ cols,
    const float* __restrict__ vals, int* __restrict__ cursor,
    int2* __restrict__ bins, const int* __restrict__ used, const int cap) {
    __shared__ int h[NB];
    const int a = blockIdx.y;
    if (!used[a]) return;
    const int tid = threadIdx.x;
    const long e0 = (long)a * E_EDGES + (long)blockIdx.x * P1_CHUNK;
    for (int i = tid; i < NB; i += P1_BLK) h[i] = 0;
    __syncthreads();
    for (int i = tid; i < P1_CHUNK; i += P1_BLK)
        atomicAdd(&h[rows[e0 + i] >> 8], 1);
    __syncthreads();
    for (int bk = tid; bk < NB; bk += P1_BLK) {
        const int c = h[bk];
        if (c) h[bk] = atomicAdd(&cursor[a * NB + bk], c);  // abs base of run
    }
    __syncthreads();
    for (int i = tid; i < P1_CHUNK; i += P1_BLK) {
        const int r  = rows[e0 + i];
        const int bk = r >> 8;
        const int slot = atomicAdd(&h[bk], 1);              // absolute bins index
        if (!cap || slot < (a * NB + bk + 1) * cap)
            bins[slot] = make_int2((cols[e0 + i] << 8) | (r & 255),
                                   __float_as_int(vals[e0 + i]));
    }
}

// ---- sort: per-bucket counting sort by r&255, emit per-row (start,count);
//      plain cacheable loads/stores (r11 ERRATA applies to writeback too);
//      records rewritten to (col<<6, val) for the gather core ----
__global__ __launch_bounds__(SORT_BLK) void sort_kernel(
    int2* __restrict__ bins, const int* __restrict__ bbase,
    const int* __restrict__ cursor, int2* __restrict__ rowinfo,
    const int* __restrict__ used) {
    __shared__ int2 stage[SORT_STAGE];
    __shared__ int h[256], off[256], cur[256], wsc[4];
    const int a   = blockIdx.x / NB;
    if (!used[a]) return;
    const int tid = threadIdx.x;
    const int bk  = blockIdx.x % NB;
    const int p0  = bbase[blockIdx.x];
    const int n   = min(cursor[blockIdx.x] - p0, SORT_STAGE);

    if (tid < 256) h[tid] = 0;
    __syncthreads();
    for (int i = tid; i < n; i += SORT_BLK) {
        const int2 e = bins[p0 + i];
        stage[i] = e;
        atomicAdd(&h[e.x & 255], 1);
    }
    __syncthreads();
    {
        const int lane = tid & 63, wave = tid >> 6;
        const int v = (tid < 256) ? h[tid] : 0;
        int incl = v;
        #pragma unroll
        for (int o = 1; o < 64; o <<= 1) {
            const int t = __shfl_up(incl, o);
            if (lane >= o) incl += t;
        }
        if (tid < 256 && lane == 63) wsc[wave] = incl;
        __syncthreads();
        if (tid == 0) {
            int run = 0;
            #pragma unroll
            for (int w = 0; w < 4; ++w) { const int t = wsc[w]; wsc[w] = run; run += t; }
        }
        __syncthreads();
        if (tid < 256) {
            const int e = incl - v + wsc[wave];
            off[tid] = e;
            cur[tid] = e;
        }
    }
    __syncthreads();
    for (int i = tid; i < n; i += SORT_BLK) {
        const int2 e = stage[i];
        const int rank = atomicAdd(&cur[e.x & 255], 1);
        bins[p0 + rank] = make_int2(((u32)e.x >> 8) << 6, e.y);
    }
    if (tid < 256) {
        const int row = (bk << 8) + tid;
        if (row < N_NODES)
            rowinfo[a * N_NODES + row] = make_int2(p0 + off[tid], h[tid]);
    }
}

// ---------------- Pull gather cores ----------
// 4-segment core (fused): round-2 structure, verbatim.
__device__ __forceinline__ void gather4(
    const u16* __restrict__ base, const u32 nvoff,
    const int2* __restrict__ bins,
    const int2 i0, const int2 i1, const int2 i2, const int2 i3,
    const int grp, const int dsub, float acc[8])
{
    const int c1 = i0.y;
    const int c2 = c1 + i1.y;
    const int c3 = c2 + i2.y;
    const int m  = c3 + i3.y;
    const int b0 = i0.x;
    const int b1 = i1.x - c1;
    const int b2 = i2.x - c2;
    const int b3 = i3.x - c3;

    for (int T = grp; T < m; T += 32) {
        int x0, x1, x2, x3;
        float v0, v1, v2, v3;
        u32 so0, so1, so2, so3;
        #define SLOT(TT, XX, VV, SS) {                                        \
            const int t = (TT);                                               \
            int pos = b0 + t;                                                 \
            if (t >= c1) pos = b1 + t;                                        \
            if (t >= c2) pos = b2 + t;                                        \
            if (t >= c3) pos = b3 + t;                                        \
            long long raw = 0;                                                \
            if (t < m)                                                        \
                raw = __builtin_nontemporal_load((const long long*)(bins + pos)); \
            XX = (int)raw;                                                    \
            VV = __int_as_float((int)(raw >> 32));                            \
            SS = (t < c2) ? nvoff : 0u; }
        SLOT(T,      x0, v0, so0)
        SLOT(T + 8,  x1, v1, so1)
        SLOT(T + 16, x2, v2, so2)
        SLOT(T + 24, x3, v3, so3)
        #undef SLOT
        const uint4 w0 = *(const uint4*)(base + (so0 + ((u32)x0 & 0xFFFFFFC0u) + (u32)dsub));
        const uint4 w1 = *(const uint4*)(base + (so1 + ((u32)x1 & 0xFFFFFFC0u) + (u32)dsub));
        const uint4 w2 = *(const uint4*)(base + (so2 + ((u32)x2 & 0xFFFFFFC0u) + (u32)dsub));
        const uint4 w3 = *(const uint4*)(base + (so3 + ((u32)x3 & 0xFFFFFFC0u) + (u32)dsub));
        #define FMA8(W, V) {                                                  \
            acc[0] = fmaf((V), __int_as_float((W).x << 16),         acc[0]);  \
            acc[1] = fmaf((V), __int_as_float((W).x & 0xffff0000u), acc[1]);  \
            acc[2] = fmaf((V), __int_as_float((W).y << 16),         acc[2]);  \
            acc[3] = fmaf((V), __int_as_float((W).y & 0xffff0000u), acc[3]);  \
            acc[4] = fmaf((V), __int_as_float((W).z << 16),         acc[4]);  \
            acc[5] = fmaf((V), __int_as_float((W).z & 0xffff0000u), acc[5]);  \
            acc[6] = fmaf((V), __int_as_float((W).w << 16),         acc[6]);  \
            acc[7] = fmaf((V), __int_as_float((W).w & 0xffff0000u), acc[7]); }
        FMA8(w0, v0)
        FMA8(w1, v1)
        FMA8(w2, v2)
        FMA8(w3, v3)
        #undef FMA8
    }
}

// 2-segment core (gather_op): no 4-way cascade, no source select.
__device__ __forceinline__ void gather2(
    const u16* __restrict__ base, const int2* __restrict__ bins,
    const int2 i0, const int2 i1,
    const int grp, const int dsub, float acc[8])
{
    const int c1 = i0.y;
    const int m  = c1 + i1.y;
    const int b0 = i0.x;
    const int b1 = i1.x - c1;

    for (int T = grp; T < m; T += 32) {
        int x0, x1, x2, x3;
        float v0, v1, v2, v3;
        #define SLOT2(TT, XX, VV) {                                           \
            const int t = (TT);                                               \
            const int pos = (t >= c1) ? (b1 + t) : (b0 + t);                  \
            long long raw = 0;                                                \
            if (t < m)                                                        \
                raw = __builtin_nontemporal_load((const long long*)(bins + pos)); \
            XX = (int)raw;                                                    \
            VV = __int_as_float((int)(raw >> 32)); }
        SLOT2(T,      x0, v0)
        SLOT2(T + 8,  x1, v1)
        SLOT2(T + 16, x2, v2)
        SLOT2(T + 24, x3, v3)
        #undef SLOT2
        const uint4 w0 = *(const uint4*)(base + (((u32)x0 & 0xFFFFFFC0u) + (u32)dsub));
        const uint4 w1 = *(const uint4*)(base + (((u32)x1 & 0xFFFFFFC0u) + (u32)dsub));
        const uint4 w2 = *(const uint4*)(base + (((u32)x2 & 0xFFFFFFC0u) + (u32)dsub));
        const uint4 w3 = *(const uint4*)(base + (((u32)x3 & 0xFFFFFFC0u) + (u32)dsub));
        #define FMA8(W, V) {                                                  \
            acc[0] = fmaf((V), __int_as_float((W).x << 16),         acc[0]);  \
            acc[1] = fmaf((V), __int_as_float((W).x & 0xffff0000u), acc[1]);  \
            acc[2] = fmaf((V), __int_as_float((W).y << 16),         acc[2]);  \
            acc[3] = fmaf((V), __int_as_float((W).y & 0xffff0000u), acc[3]);  \
            acc[4] = fmaf((V), __int_as_float((W).z << 16),         acc[4]);  \
            acc[5] = fmaf((V), __int_as_float((W).z & 0xffff0000u), acc[5]);  \
            acc[6] = fmaf((V), __int_as_float((W).w << 16),         acc[6]);  \
            acc[7] = fmaf((V), __int_as_float((W).w & 0xffff0000u), acc[7]); }
        FMA8(w0, v0)
        FMA8(w1, v1)
        FMA8(w2, v2)
        FMA8(w3, v3)
        #undef FMA8
    }
}

__device__ __forceinline__ void reduce_groups8(float acc[8]) {
    #pragma unroll
    for (int d = 0; d < 8; ++d) {
        acc[d] += __shfl_xor(acc[d], 8);
        acc[d] += __shfl_xor(acc[d], 16);
        acc[d] += __shfl_xor(acc[d], 32);
    }
}

// s1 = bf16(0.5*(A[i0]+A[i1]) @ s0)
__global__ __launch_bounds__(256) void gather_op_kernel(
    const u16* __restrict__ s0, u16* __restrict__ dst,
    const int2* __restrict__ bins, const int2* __restrict__ rowinfo,
    const int* __restrict__ idx) {
    const int lane = threadIdx.x & 63;
    const int row  = blockIdx.x * 4 + (threadIdx.x >> 6);
    const int grp  = lane >> 3;
    const int sub  = lane & 7;
    const int dsub = sub << 3;
    const int2 i0 = rowinfo[idx[0] * N_NODES + row];
    const int2 i1 = rowinfo[idx[1] * N_NODES + row];
    float acc[8] = {0.f, 0.f, 0.f, 0.f, 0.f, 0.f, 0.f, 0.f};
    gather2(s0, bins, i0, i1, grp, dsub, acc);
    reduce_groups8(acc);
    if (grp == 0) {
        u32 p[4];
        #pragma unroll
        for (int q = 0; q < 4; ++q) {
            __hip_bfloat16 blo = __float2bfloat16(0.5f * acc[2 * q]);
            __hip_bfloat16 bhi = __float2bfloat16(0.5f * acc[2 * q + 1]);
            p[q] = (u32)(*(u16*)&blo) | ((u32)(*(u16*)&bhi) << 16);
        }
        *(uint4*)(dst + (long)row * DIM + dsub) = make_uint4(p[0], p[1], p[2], p[3]);
    }
}

// out = gelu(LN(0.5*(seq@s1) + 0.5*(res@s0)))
__global__ __launch_bounds__(256) void fused_op_ln_gelu_kernel(
    const u16* __restrict__ s0, float* __restrict__ out,
    const int2* __restrict__ bins, const int2* __restrict__ rowinfo,
    const int* __restrict__ idx_seq1, const int* __restrict__ idx_res,
    const float* __restrict__ gamma, const float* __restrict__ beta) {
    const int lane = threadIdx.x & 63;
    const int row  = blockIdx.x * 4 + (threadIdx.x >> 6);
    const int grp  = lane >> 3;
    const int sub  = lane & 7;
    const int dsub = sub << 3;
    // segments 0,1 gather from s1 (= s0 + NVOFF via nvoff), 2,3 from s0
    const int2 i0 = rowinfo[idx_seq1[0] * N_NODES + row];
    const int2 i1 = rowinfo[idx_seq1[1] * N_NODES + row];
    const int2 i2 = rowinfo[idx_res[0]  * N_NODES + row];
    const int2 i3 = rowinfo[idx_res[1]  * N_NODES + row];
    float acc[8] = {0.f, 0.f, 0.f, 0.f, 0.f, 0.f, 0.f, 0.f};
    gather4(s0, NVOFF, bins, i0, i1, i2, i3, grp, dsub, acc);
    reduce_groups8(acc);
    #pragma unroll
    for (int d = 0; d < 8; ++d) acc[d] *= 0.5f;
    float s = 0.f, s2 = 0.f;
    #pragma unroll
    for (int d = 0; d < 8; ++d) { s += acc[d]; s2 += acc[d] * acc[d]; }
    s  += __shfl_xor(s, 1);  s  += __shfl_xor(s, 2);  s  += __shfl_xor(s, 4);
    s2 += __shfl_xor(s2, 1); s2 += __shfl_xor(s2, 2); s2 += __shfl_xor(s2, 4);
    const float mu  = s * (1.0f / DIM);
    const float var = s2 * (1.0f / DIM) - mu * mu;
    const float inv = rsqrtf(var + 1e-5f);
    if (grp == 0) {
        const float4 gm0 = ((const float4*)gamma)[sub * 2];
        const float4 gm1 = ((const float4*)gamma)[sub * 2 + 1];
        const float4 bt0 = ((const float4*)beta)[sub * 2];
        const float4 bt1 = ((const float4*)beta)[sub * 2 + 1];
        float y[8];
        y[0] = (acc[0] - mu) * inv * gm0.x + bt0.x;
        y[1] = (acc[1] - mu) * inv * gm0.y + bt0.y;
        y[2] = (acc[2] - mu) * inv * gm0.z + bt0.z;
        y[3] = (acc[3] - mu) * inv * gm0.w + bt0.w;
        y[4] = (acc[4] - mu) * inv * gm1.x + bt1.x;
        y[5] = (acc[5] - mu) * inv * gm1.y + bt1.y;
        y[6] = (acc[6] - mu) * inv * gm1.z + bt1.z;
        y[7] = (acc[7] - mu) * inv * gm1.w + bt1.w;
        f32x4 o0, o1;
        o0.x = 0.5f * y[0] * (1.0f + erff(y[0] * 0.70710678118654752f));
        o0.y = 0.5f * y[1] * (1.0f + erff(y[1] * 0.70710678118654752f));
        o0.z = 0.5f * y[2] * (1.0f + erff(y[2] * 0.70710678118654752f));
        o0.w = 0.5f * y[3] * (1.0f + erff(y[3] * 0.70710678118654752f));
        o1.x = 0.5f * y[4] * (1.0f + erff(y[4] * 0.70710678118654752f));
        o1.y = 0.5f * y[5] * (1.0f + erff(y[5] * 0.70710678118654752f));
        o1.z = 0.5f * y[6] * (1.0f + erff(y[6] * 0.70710678118654752f));
        o1.w = 0.5f * y[7] * (1.0f + erff(y[7] * 0.70710678118654752f));
        // final output: dense wave-contiguous stores -> nt is safe here
        // (measured fine r9/r10); keeps L2 for the gather tables
        f32x4* po = (f32x4*)(out + (long)row * DIM + dsub);
        __builtin_nontemporal_store(o0, po);
        __builtin_nontemporal_store(o1, po + 1);
    }
}

extern "C" void kernel_launch(void* const* d_in, const int* in_sizes, int n_in,
                              void* d_out, int out_size, void* d_ws, size_t ws_size,
                              hipStream_t stream) {
    const float* x     = (const float*)d_in[0];
    const float* W     = (const float*)d_in[1];
    const float* b     = (const float*)d_in[2];
    const int*   rows  = (const int*)d_in[3];
    const int*   cols  = (const int*)d_in[4];
    const float* vals  = (const float*)d_in[5];
    const float* gamma = (const float*)d_in[6];
    const float* beta  = (const float*)d_in[7];
    const int*   idxes_seq = (const int*)d_in[8];   // [2,2] flat
    const int*   idxes_res = (const int*)d_in[9];   // [1,2] flat
    float* out = (float*)d_out;

    // ---- mode select: fixed-cap bins (skip hist+scan) if workspace allows ----
    const size_t tail_bytes = (size_t)N_NODES * DIM * 2 * 2        // s0+s1
                            + (size_t)N_ADJ * N_NODES * 8          // rowinfo
                            + (size_t)(NBTOT + NBTOT + 1 + NBTOT + 4) * 4;
    const size_t fixed_need = (size_t)NBTOT * CAP * 8 + tail_bytes;
    const int mode = (ws_size >= fixed_need) ? 1 : 0;
    const size_t bins_elems = mode ? (size_t)NBTOT * CAP
                                   : (size_t)N_ADJ * E_EDGES;

    int2*  bins    = (int2*)d_ws;
    u16*   s0      = (u16*)(bins + bins_elems);                  // 12.8 MB bf16
    u16*   s1      = s0 + (size_t)N_NODES * DIM;                 // 12.8 MB (= s0 + NVOFF)
    int2*  rowinfo = (int2*)(s1 + (size_t)N_NODES * DIM);        // 3.2 MB
    int*   gcnt    = (int*)(rowinfo + (size_t)N_ADJ * N_NODES);  // 1564 ints
    int*   bbase   = gcnt + NBTOT;                               // 1565 ints
    int*   cursor  = bbase + NBTOT + 1;                          // 1564 ints
    int*   used    = cursor + NBTOT;                             // 4 ints

    // gemm + init fused: block GEMM_BLOCKS performs mask/cursor init
    gemm_init_kernel<<<GEMM_BLOCKS + 1, 256, 0, stream>>>(
        x, W, b, s0, idxes_seq, idxes_res, used, gcnt, bbase, cursor, mode);

    dim3 egrid(P1_GRIDX, N_ADJ);
    if (!mode) {
        hist_kernel<<<egrid, P1_BLK, 0, stream>>>(rows, gcnt, used);
        scan_kernel<<<1, P1_BLK, 0, stream>>>(gcnt, bbase, cursor);
    }
    place_kernel<<<egrid, P1_BLK, 0, stream>>>(rows, cols, vals, cursor, bins,
                                               used, mode ? CAP : 0);
    sort_kernel<<<NBTOT, SORT_BLK, 0, stream>>>(bins, bbase, cursor, rowinfo, used);

    // s1 = 0.5*(A[i0]+A[i1]) @ s0
    gather_op_kernel<<<N_NODES / 4, 256, 0, stream>>>(s0, s1, bins, rowinfo, idxes_seq);
    // out = gelu(LN(0.5*(A[i2]+A[i3])@s1 + 0.5*(A[r0]+A[r1])@s0))
    fused_op_ln_gelu_kernel<<<N_NODES / 4, 256, 0, stream>>>(
        s0, out, bins, rowinfo, idxes_seq + 2, idxes_res, gamma, beta);
}